// Round 1
// baseline (1177.570 us; speedup 1.0000x reference)
//
#include <hip/hip_runtime.h>

namespace {
constexpr int ICH = 8, IH = 128, IW = 128;
constexpr int OW = 126;
constexpr int CPG = 4, PH = 31;
constexpr float EPS = 1e-5f;

__device__ __forceinline__ int swz(int chunk) { return chunk ^ ((chunk >> 3) & 3); }

__device__ __forceinline__ unsigned int f2bf(float f) {
  unsigned int u = __float_as_uint(f);
  return (u + 0x7fffu + ((u >> 16) & 1u)) >> 16;  // round-to-nearest-even bf16
}
__device__ __forceinline__ float bf2f(unsigned int b) { return __uint_as_float(b << 16); }

__global__ __launch_bounds__(256, 3) void fused_conv_gn_pool(
    const float* __restrict__ x, const float* __restrict__ cw,
    const float* __restrict__ cb, const float* __restrict__ gnw,
    const float* __restrict__ gnb, const float* __restrict__ sc,
    float* __restrict__ out) {
  __shared__ float strip[ICH][6][132];        // input rows, swizzled 4-float chunks
  __shared__ float convb[CPG][4][132];        // conv out for one window-row
  __shared__ unsigned int mm[CPG][PH][PH];    // packed bf16 (max<<16)|min per window
  __shared__ float red[8];
  __shared__ float stats[2];

  const int bid = blockIdx.x;
  // XCD-aware swizzle: all 16 groups of an image land on the same XCD's L2.
  const int xcd = bid & 7;
  const int k = bid >> 3;          // 0..255
  const int n = xcd * 16 + (k >> 4);
  const int g = k & 15;
  const int t = threadIdx.x;

  const int c  = t >> 6;   // wave id = local channel 0..3
  const int u  = t & 63;
  const int r0 = u >> 5;   // 0..1
  const int j  = u & 31;   // col-chunk 0..31 (cols 4j..4j+3)

  const int gc = g * CPG + c;
  float wr[8][3][3];
  {
    const float* wp = cw + gc * 72;
#pragma unroll
    for (int ic = 0; ic < 8; ++ic)
#pragma unroll
      for (int a = 0; a < 3; ++a)
#pragma unroll
        for (int b = 0; b < 3; ++b) wr[ic][a][b] = wp[(ic * 3 + a) * 3 + b];
  }
  const float bias = cb[gc];

  float s1 = 0.f, s2 = 0.f;
  const float* xn = x + (size_t)n * ICH * IH * IW;

  for (int wh = 0; wh < PH; ++wh) {
    __syncthreads();
    // ---- Phase A: stage input rows 4wh..4wh+5 (8ch x 6rows x 128cols) ----
    const int br = 4 * wh;
#pragma unroll
    for (int kk = 0; kk < 6; ++kk) {
      int f = t + kk * 256;          // 0..1535 float4 chunks
      int ic = f / 192;
      int rem = f - ic * 192;
      int row = rem >> 5;
      int ch = rem & 31;
      float4 v = *reinterpret_cast<const float4*>(xn + ((size_t)ic * IH + br + row) * IW + ch * 4);
      *reinterpret_cast<float4*>(&strip[ic][row][swz(ch) * 4]) = v;
    }
    __syncthreads();
    // ---- Phase B: conv 4 output rows, accumulate stats ----
#pragma unroll
    for (int tk = 0; tk < 2; ++tk) {
      const int r = r0 + 2 * tk;     // output row within window-row: 0..3
      float a0 = 0.f, a1 = 0.f, a2 = 0.f, a3 = 0.f;
#pragma unroll
      for (int ic = 0; ic < 8; ++ic) {
        float in6[3][6];
#pragma unroll
        for (int dh = 0; dh < 3; ++dh) {
          float4 v4 = *reinterpret_cast<const float4*>(&strip[ic][r + dh][swz(j) * 4]);
          float2 v2 = *reinterpret_cast<const float2*>(&strip[ic][r + dh][swz(j + 1) * 4]);
          in6[dh][0] = v4.x; in6[dh][1] = v4.y; in6[dh][2] = v4.z; in6[dh][3] = v4.w;
          in6[dh][4] = v2.x; in6[dh][5] = v2.y;
        }
#pragma unroll
        for (int dh = 0; dh < 3; ++dh)
#pragma unroll
          for (int dw = 0; dw < 3; ++dw) {
            const float wv = wr[ic][dh][dw];
            a0 = fmaf(in6[dh][dw + 0], wv, a0);
            a1 = fmaf(in6[dh][dw + 1], wv, a1);
            a2 = fmaf(in6[dh][dw + 2], wv, a2);
            a3 = fmaf(in6[dh][dw + 3], wv, a3);
          }
      }
      a0 += bias; a1 += bias; a2 += bias; a3 += bias;
      *reinterpret_cast<float4*>(&convb[c][r][swz(j) * 4]) = make_float4(a0, a1, a2, a3);
      if (j < 31) {  // cols 4j..4j+3 all < 126
        s1 += a0 + a1 + a2 + a3;
        s2 += a0 * a0 + a1 * a1 + a2 * a2 + a3 * a3;
      } else {       // j==31: only cols 124,125 valid
        s1 += a0 + a1;
        s2 += a0 * a0 + a1 * a1;
      }
    }
    __syncthreads();
    // ---- Phase C: per-window max/min for this window-row ----
    if (t < CPG * PH) {
      int cc = t / PH, ww = t - (t / PH) * PH;
      float mx = -3.4e38f, mn = 3.4e38f;
#pragma unroll
      for (int r = 0; r < 4; ++r) {
        float4 v = *reinterpret_cast<const float4*>(&convb[cc][r][swz(ww) * 4]);
        mx = fmaxf(mx, fmaxf(fmaxf(v.x, v.y), fmaxf(v.z, v.w)));
        mn = fminf(mn, fminf(fminf(v.x, v.y), fminf(v.z, v.w)));
      }
      mm[cc][wh][ww] = (f2bf(mx) << 16) | f2bf(mn);
    }
  }

  // ---- Leftover output rows 124,125 (stats only, dropped by floor-pooling) ----
  __syncthreads();
#pragma unroll
  for (int kk = 0; kk < 4; ++kk) {
    int f = t + kk * 256;  // 0..1023: 8ch x 4rows x 32chunks
    int ic = f >> 7;
    int rem = f & 127;
    int row = rem >> 5;
    int ch = rem & 31;
    float4 v = *reinterpret_cast<const float4*>(xn + ((size_t)ic * IH + 124 + row) * IW + ch * 4);
    *reinterpret_cast<float4*>(&strip[ic][row][swz(ch) * 4]) = v;
  }
  __syncthreads();
  {
    const int r = r0;  // output row 124+r
    float a0 = 0.f, a1 = 0.f, a2 = 0.f, a3 = 0.f;
#pragma unroll
    for (int ic = 0; ic < 8; ++ic) {
      float in6[3][6];
#pragma unroll
      for (int dh = 0; dh < 3; ++dh) {
        float4 v4 = *reinterpret_cast<const float4*>(&strip[ic][r + dh][swz(j) * 4]);
        float2 v2 = *reinterpret_cast<const float2*>(&strip[ic][r + dh][swz(j + 1) * 4]);
        in6[dh][0] = v4.x; in6[dh][1] = v4.y; in6[dh][2] = v4.z; in6[dh][3] = v4.w;
        in6[dh][4] = v2.x; in6[dh][5] = v2.y;
      }
#pragma unroll
      for (int dh = 0; dh < 3; ++dh)
#pragma unroll
        for (int dw = 0; dw < 3; ++dw) {
          const float wv = wr[ic][dh][dw];
          a0 = fmaf(in6[dh][dw + 0], wv, a0);
          a1 = fmaf(in6[dh][dw + 1], wv, a1);
          a2 = fmaf(in6[dh][dw + 2], wv, a2);
          a3 = fmaf(in6[dh][dw + 3], wv, a3);
        }
    }
    a0 += bias; a1 += bias; a2 += bias; a3 += bias;
    if (j < 31) {
      s1 += a0 + a1 + a2 + a3;
      s2 += a0 * a0 + a1 * a1 + a2 * a2 + a3 * a3;
    } else {
      s1 += a0 + a1;
      s2 += a0 * a0 + a1 * a1;
    }
  }

  // ---- block reduction of sum / sumsq ----
#pragma unroll
  for (int off = 32; off > 0; off >>= 1) {
    s1 += __shfl_down(s1, off, 64);
    s2 += __shfl_down(s2, off, 64);
  }
  if (u == 0) { red[c * 2] = s1; red[c * 2 + 1] = s2; }
  __syncthreads();
  if (t == 0) {
    float S1 = red[0] + red[2] + red[4] + red[6];
    float S2 = red[1] + red[3] + red[5] + red[7];
    constexpr float invN = 1.f / (CPG * 126.f * 126.f);
    float mean = S1 * invN;
    float var = S2 * invN - mean * mean;
    stats[0] = mean;
    stats[1] = rsqrtf(var + EPS);
  }
  __syncthreads();
  const float mean = stats[0], inv = stats[1];

  // ---- epilogue: affine + pool-select + clamp + store ----
  float* outp = out + ((size_t)n * 64 + g * CPG) * (PH * PH);
  for (int kk = 0; kk < 16; ++kk) {
    int idx = t + kk * 256;
    if (idx < CPG * PH * PH) {
      int cc = idx / (PH * PH);
      int rem = idx - cc * (PH * PH);
      unsigned int p = mm[cc][rem / PH][rem - (rem / PH) * PH];
      int gcc = g * CPG + cc;
      float gw = gnw[gcc];
      float A = gw * inv * sc[gcc];
      float B = (gnb[gcc] - mean * inv * gw) * sc[gcc];
      float v = A * (A > 0.f ? bf2f(p >> 16) : bf2f(p & 0xffffu)) + B;
      v = fminf(fmaxf(v, 0.f), 1.f);
      outp[cc * (PH * PH) + rem] = v;
    }
  }
}
}  // namespace

extern "C" void kernel_launch(void* const* d_in, const int* in_sizes, int n_in,
                              void* d_out, int out_size, void* d_ws, size_t ws_size,
                              hipStream_t stream) {
  const float* x   = (const float*)d_in[0];
  const float* cw  = (const float*)d_in[1];
  const float* cb  = (const float*)d_in[2];
  const float* gnw = (const float*)d_in[3];
  const float* gnb = (const float*)d_in[4];
  const float* sc  = (const float*)d_in[5];
  float* out = (float*)d_out;
  hipLaunchKernelGGL(fused_conv_gn_pool, dim3(2048), dim3(256), 0, stream,
                     x, cw, cb, gnw, gnb, sc, out);
}